// Round 9
// baseline (315.443 us; speedup 1.0000x reference)
//
#include <hip/hip_runtime.h>
#include <hip/hip_bf16.h>
#include <stdint.h>

// KAN-like regressor: N=65536, D=32 features, H=128.
// R8: INSTRUMENTATION ROUND. Real kernel = R6 (atomics, known-good 109us).
// Plus 3 probe dispatches into d_ws that ablate the loop body:
//   probe<1> = MFMA chains only (no pack/epi/mem)  -> MFMA issue+latency cost
//   probe<0> = MFMA + relu_pack coupling + epi     -> + VALU/coupling cost
//   probe<2> = LDS reads + plain stores only       -> memory-side cost
// Each probe mirrors R6's init, register pressure, grid 512, lb(256,2), 32 bodies.

#define D_FEAT 32
#define H_DIM  128
#define N_TOT  65536
#define SLOTS  16
#define THREADS 256
#define NTILE  64

typedef float    f32x16 __attribute__((ext_vector_type(16)));
typedef short    bf16x8 __attribute__((ext_vector_type(8)));
typedef uint32_t u32;

static __device__ __forceinline__ u32 cvtpk(float lo, float hi) {
    u32 r;
    asm("v_cvt_pk_bf16_f32 %0, %1, %2" : "=v"(r) : "v"(lo), "v"(hi));
    return r;
}
static __device__ __forceinline__ bf16x8 frag4(u32 a, u32 b, u32 c, u32 d) {
    int4 t = make_int4((int)a, (int)b, (int)c, (int)d);
    return __builtin_bit_cast(bf16x8, t);
}
static __device__ __forceinline__ bf16x8 frag1(u32 a) { return frag4(a, 0u, 0u, 0u); }

#define MFMA32(A, B, C) __builtin_amdgcn_mfma_f32_32x32x16_bf16((A), (B), (C), 0, 0, 0)

static __device__ __forceinline__ bf16x8 relu_pack(const f32x16& v, int s) {
    u32 c0 = cvtpk(fmaxf(v[8*s+0], 0.f), fmaxf(v[8*s+1], 0.f));
    u32 c1 = cvtpk(fmaxf(v[8*s+2], 0.f), fmaxf(v[8*s+3], 0.f));
    u32 c2 = cvtpk(fmaxf(v[8*s+4], 0.f), fmaxf(v[8*s+5], 0.f));
    u32 c3 = cvtpk(fmaxf(v[8*s+6], 0.f), fmaxf(v[8*s+7], 0.f));
    return frag4(c0, c1, c2, c3);
}

static __device__ __forceinline__ float epi(const f32x16& a0, const f32x16& a1,
                                            const float* __restrict__ W3s,
                                            int mo0, int mo1, int g) {
    float p[4];
#pragma unroll
    for (int q = 0; q < 4; ++q) {
        const float4 wa = *reinterpret_cast<const float4*>(&W3s[32 * mo0 + 4 * g + 8 * q]);
        const float4 wb = *reinterpret_cast<const float4*>(&W3s[32 * mo1 + 4 * g + 8 * q]);
        float t;
        t = fmaxf(a0[4*q+0], 0.f) * wa.x;
        t = fmaf(fmaxf(a0[4*q+1], 0.f), wa.y, t);
        t = fmaf(fmaxf(a0[4*q+2], 0.f), wa.z, t);
        t = fmaf(fmaxf(a0[4*q+3], 0.f), wa.w, t);
        t = fmaf(fmaxf(a1[4*q+0], 0.f), wb.x, t);
        t = fmaf(fmaxf(a1[4*q+1], 0.f), wb.y, t);
        t = fmaf(fmaxf(a1[4*q+2], 0.f), wb.z, t);
        t = fmaf(fmaxf(a1[4*q+3], 0.f), wb.w, t);
        p[q] = t;
    }
    return (p[0] + p[1]) + (p[2] + p[3]);
}

// ---------------- REAL kernel: R6 verbatim ----------------
__global__ __launch_bounds__(THREADS, 2) void kan_main(
    const float* __restrict__ x, const float* __restrict__ W1,
    const float* __restrict__ b1, const float* __restrict__ W2,
    const float* __restrict__ b2, const float* __restrict__ W3,
    const float* __restrict__ b3, float* __restrict__ out)
{
    __shared__ float xall[NTILE * 64];
    __shared__ float W3s[H_DIM];

    const int tid   = threadIdx.x;
    const int d     = blockIdx.x / SLOTS;
    const int bslot = blockIdx.x % SLOTS;
    const int w     = tid >> 6;
    const int wm    = w >> 1;
    const int wn    = w & 1;
    const int l     = tid & 63;
    const int l31   = l & 31;
    const int g     = l >> 5;

#pragma unroll
    for (int i = 0; i < (NTILE * 64) / THREADS; ++i) {
        int idx = tid + THREADS * i;
        int tl  = idx >> 6;
        xall[idx] = x[(size_t)((bslot + SLOTS * tl) * 64 + (idx & 63)) * D_FEAT + d];
    }
    if (tid < H_DIM) W3s[tid] = W3[d * H_DIM + tid];

    float b3s = 0.f;
#pragma unroll
    for (int k = 0; k < D_FEAT; ++k) b3s += b3[k];

    const int mo0 = 2 * wm, mo1 = 2 * wm + 1;
    u32 w1b1[4], b2w[2];
#pragma unroll
    for (int mt = 0; mt < 4; ++mt) {
        int m = 32 * mt + l31;
        u32 v = cvtpk(W1[d * H_DIM + m], b1[d * H_DIM + m]);
        w1b1[mt] = g ? 0u : v;
    }
    b2w[0] = g ? 0u : cvtpk(b2[d * H_DIM + 32 * mo0 + l31], 0.f);
    b2w[1] = g ? 0u : cvtpk(b2[d * H_DIM + 32 * mo1 + l31], 0.f);
    const bf16x8 onesB = frag1(g ? 0u : 0x00003F80u);

    bf16x8 w2f[2][8];
    {
        const float* W2d = W2 + (size_t)d * H_DIM * H_DIM;
#pragma unroll
        for (int j = 0; j < 2; ++j) {
            int mm = 32 * (mo0 + j) + l31;
#pragma unroll
            for (int ks = 0; ks < 8; ++ks) {
                u32 dw[4];
#pragma unroll
                for (int p = 0; p < 4; ++p) {
                    int e0 = 2 * p, e1 = 2 * p + 1;
                    int k0 = 16 * ks + 4 * g + (e0 & 3) + 8 * (e0 >> 2);
                    int k1 = 16 * ks + 4 * g + (e1 & 3) + 8 * (e1 >> 2);
                    dw[p] = cvtpk(W2d[(size_t)k0 * H_DIM + mm],
                                  W2d[(size_t)k1 * H_DIM + mm]);
                }
                w2f[j][ks] = frag4(dw[0], dw[1], dw[2], dw[3]);
            }
        }
    }
    __syncthreads();

    const f32x16 zc = {};
    const bool addb3 = (d == 0) && (wm == 0);

    for (int ip = 0; ip < NTILE; ip += 2) {
        const int rb0 = (bslot + SLOTS * (ip + 0)) * 64 + 32 * wn;
        const int rb1 = (bslot + SLOTS * (ip + 1)) * 64 + 32 * wn;
        float xv0 = xall[(ip + 0) * 64 + 32 * wn + l31];
        float xv1 = xall[(ip + 1) * 64 + 32 * wn + l31];
        bf16x8 Bx0 = frag1(g ? 0u : cvtpk(xv0, 1.0f));
        bf16x8 Bx1 = frag1(g ? 0u : cvtpk(xv1, 1.0f));

        f32x16 a00 = MFMA32(frag1(b2w[0]), onesB, zc);
        f32x16 a01 = MFMA32(frag1(b2w[1]), onesB, zc);
        f32x16 a10 = MFMA32(frag1(b2w[0]), onesB, zc);
        f32x16 a11 = MFMA32(frag1(b2w[1]), onesB, zc);

#pragma unroll
        for (int mt = 0; mt < 4; ++mt) {
            f32x16 d10 = MFMA32(frag1(w1b1[mt]), Bx0, zc);
            f32x16 d11 = MFMA32(frag1(w1b1[mt]), Bx1, zc);
            bf16x8 bl0 = relu_pack(d10, 0), bh0 = relu_pack(d10, 1);
            bf16x8 bl1 = relu_pack(d11, 0), bh1 = relu_pack(d11, 1);
            a00 = MFMA32(w2f[0][2 * mt + 0], bl0, a00);
            a10 = MFMA32(w2f[0][2 * mt + 0], bl1, a10);
            a01 = MFMA32(w2f[1][2 * mt + 0], bl0, a01);
            a11 = MFMA32(w2f[1][2 * mt + 0], bl1, a11);
            a00 = MFMA32(w2f[0][2 * mt + 1], bh0, a00);
            a10 = MFMA32(w2f[0][2 * mt + 1], bh1, a10);
            a01 = MFMA32(w2f[1][2 * mt + 1], bh0, a01);
            a11 = MFMA32(w2f[1][2 * mt + 1], bh1, a11);
        }

        float rs0 = epi(a00, a01, W3s, mo0, mo1, g);
        float rs1 = epi(a10, a11, W3s, mo0, mo1, g);
        rs0 += __shfl_xor(rs0, 32, 64);
        rs1 += __shfl_xor(rs1, 32, 64);
        if (addb3) { rs0 += b3s; rs1 += b3s; }
        if (!g) {
            atomicAdd(&out[rb0 + l31], rs0);
            atomicAdd(&out[rb1 + l31], rs1);
        }
    }
}

// ---------------- PROBES ----------------
// V=0: MFMA + pack/epi coupling, no loop memory. V=1: MFMA chains only.
// V=2: LDS reads + plain stores only.
template <int V>
__global__ __launch_bounds__(THREADS, 2) void kan_probe(
    const float* __restrict__ x, const float* __restrict__ W1,
    const float* __restrict__ b1, const float* __restrict__ W2,
    const float* __restrict__ b2, const float* __restrict__ W3,
    const float* __restrict__ b3, float* __restrict__ ws)
{
    __shared__ float xall[NTILE * 64];
    __shared__ float W3s[H_DIM];

    const int tid   = threadIdx.x;
    const int d     = blockIdx.x / SLOTS;
    const int bslot = blockIdx.x % SLOTS;
    const int w     = tid >> 6;
    const int wm    = w >> 1;
    const int wn    = w & 1;
    const int l     = tid & 63;
    const int l31   = l & 31;
    const int g     = l >> 5;

#pragma unroll
    for (int i = 0; i < (NTILE * 64) / THREADS; ++i) {
        int idx = tid + THREADS * i;
        int tl  = idx >> 6;
        xall[idx] = x[(size_t)((bslot + SLOTS * tl) * 64 + (idx & 63)) * D_FEAT + d];
    }
    if (tid < H_DIM) W3s[tid] = W3[d * H_DIM + tid];

    const int mo0 = 2 * wm, mo1 = 2 * wm + 1;
    u32 w1b1[4], b2w[2];
#pragma unroll
    for (int mt = 0; mt < 4; ++mt) {
        int m = 32 * mt + l31;
        u32 v = cvtpk(W1[d * H_DIM + m], b1[d * H_DIM + m]);
        w1b1[mt] = g ? 0u : v;
    }
    b2w[0] = g ? 0u : cvtpk(b2[d * H_DIM + 32 * mo0 + l31], 0.f);
    b2w[1] = g ? 0u : cvtpk(b2[d * H_DIM + 32 * mo1 + l31], 0.f);
    const bf16x8 onesB = frag1(g ? 0u : 0x00003F80u);

    bf16x8 w2f[2][8];
    {
        const float* W2d = W2 + (size_t)d * H_DIM * H_DIM;
#pragma unroll
        for (int j = 0; j < 2; ++j) {
            int mm = 32 * (mo0 + j) + l31;
#pragma unroll
            for (int ks = 0; ks < 8; ++ks) {
                u32 dw[4];
#pragma unroll
                for (int p = 0; p < 4; ++p) {
                    int e0 = 2 * p, e1 = 2 * p + 1;
                    int k0 = 16 * ks + 4 * g + (e0 & 3) + 8 * (e0 >> 2);
                    int k1 = 16 * ks + 4 * g + (e1 & 3) + 8 * (e1 >> 2);
                    dw[p] = cvtpk(W2d[(size_t)k0 * H_DIM + mm],
                                  W2d[(size_t)k1 * H_DIM + mm]);
                }
                w2f[j][ks] = frag4(dw[0], dw[1], dw[2], dw[3]);
            }
        }
    }
    __syncthreads();

    const f32x16 zc = {};
    float keep = 0.f;
    float* const wsW = ws + (size_t)(V + 1) * (1u << 20);   // disjoint probe slices

    for (int ip = 0; ip < NTILE; ip += 2) {
        if (V == 2) {
            // memory-only body: 2 LDS reads + 2 plain stores (R6 addresses)
            const int rb0 = (bslot + SLOTS * (ip + 0)) * 64 + 32 * wn;
            const int rb1 = (bslot + SLOTS * (ip + 1)) * 64 + 32 * wn;
            float xv0 = xall[(ip + 0) * 64 + 32 * wn + l31];
            float xv1 = xall[(ip + 1) * 64 + 32 * wn + l31];
            float r0 = fmaf(xv0, 1.0001f, keep * 1e-30f);
            float r1 = xv1 * 1.0001f;
            if (!g) { wsW[rb0 + l31] = r0; wsW[rb1 + l31] = r1; }
            keep = fmaf(r1, 1e-30f, keep);
        } else {
            // no loop memory: synthetic x
            float xv0 = (float)(ip + l31) * 0.01f;
            float xv1 = xv0 + 0.5f;
            bf16x8 Bx0 = frag1(g ? 0u : cvtpk(xv0, 1.0f));
            bf16x8 Bx1 = frag1(g ? 0u : cvtpk(xv1, 1.0f));

            f32x16 a00 = MFMA32(frag1(b2w[0]), onesB, zc);
            f32x16 a01 = MFMA32(frag1(b2w[1]), onesB, zc);
            f32x16 a10 = MFMA32(frag1(b2w[0]), onesB, zc);
            f32x16 a11 = MFMA32(frag1(b2w[1]), onesB, zc);

#pragma unroll
            for (int mt = 0; mt < 4; ++mt) {
                f32x16 d10 = MFMA32(frag1(w1b1[mt]), Bx0, zc);
                f32x16 d11 = MFMA32(frag1(w1b1[mt]), Bx1, zc);
                bf16x8 bl0, bh0, bl1, bh1;
                if (V == 0) {
                    bl0 = relu_pack(d10, 0); bh0 = relu_pack(d10, 1);
                    bl1 = relu_pack(d11, 0); bh1 = relu_pack(d11, 1);
                } else {
                    // V=1: break h1->chain coupling; keep h1 MFMAs live cheaply
                    bl0 = frag1(b2w[0]); bh0 = frag1(b2w[1]);
                    bl1 = frag1(w1b1[0]); bh1 = frag1(w1b1[1]);
                    keep += d10[0] + d11[0];
                }
                a00 = MFMA32(w2f[0][2 * mt + 0], bl0, a00);
                a10 = MFMA32(w2f[0][2 * mt + 0], bl1, a10);
                a01 = MFMA32(w2f[1][2 * mt + 0], bl0, a01);
                a11 = MFMA32(w2f[1][2 * mt + 0], bh1, a11);
                a00 = MFMA32(w2f[0][2 * mt + 1], bh0, a00);
                a10 = MFMA32(w2f[0][2 * mt + 1], bh1, a10);
                a01 = MFMA32(w2f[1][2 * mt + 1], bh0, a01);
                a11 = MFMA32(w2f[1][2 * mt + 1], bl1, a11);
            }

            if (V == 0) {
                float rs0 = epi(a00, a01, W3s, mo0, mo1, g);
                float rs1 = epi(a10, a11, W3s, mo0, mo1, g);
                rs0 += __shfl_xor(rs0, 32, 64);
                rs1 += __shfl_xor(rs1, 32, 64);
                keep += rs0 + rs1;
            } else {
                keep += a00[0] + a01[0] + a10[0] + a11[0];
            }
        }
    }

    // keep all register state live; one store per thread
    float fold = keep;
#pragma unroll
    for (int j = 0; j < 2; ++j)
#pragma unroll
        for (int ks = 0; ks < 8; ++ks) fold += (float)w2f[j][ks][0];
    fold += W3s[l] * 1e-30f;
    wsW[(1u << 19) + (size_t)blockIdx.x * THREADS + tid] = fold;
}

extern "C" void kernel_launch(void* const* d_in, const int* in_sizes, int n_in,
                              void* d_out, int out_size, void* d_ws, size_t ws_size,
                              hipStream_t stream) {
    const float* x  = (const float*)d_in[0];
    const float* W1 = (const float*)d_in[1];
    const float* b1 = (const float*)d_in[2];
    const float* W2 = (const float*)d_in[3];
    const float* b2 = (const float*)d_in[4];
    const float* W3 = (const float*)d_in[5];
    const float* b3 = (const float*)d_in[6];
    float* out = (float*)d_out;

    hipMemsetAsync(out, 0, (size_t)N_TOT * sizeof(float), stream);
    kan_main<<<D_FEAT * SLOTS, THREADS, 0, stream>>>(x, W1, b1, W2, b2, W3, b3, out);

    if (ws_size >= (size_t)4 * (1u << 20) * sizeof(float)) {
        float* ws = (float*)d_ws;
        kan_probe<1><<<D_FEAT * SLOTS, THREADS, 0, stream>>>(x, W1, b1, W2, b2, W3, b3, ws);
        kan_probe<0><<<D_FEAT * SLOTS, THREADS, 0, stream>>>(x, W1, b1, W2, b2, W3, b3, ws);
        kan_probe<2><<<D_FEAT * SLOTS, THREADS, 0, stream>>>(x, W1, b1, W2, b2, W3, b3, ws);
    }
}